// Round 5
// baseline (2605.955 us; speedup 1.0000x reference)
//
#include <hip/hip_runtime.h>
#include <cstdint>

using u16 = unsigned short;
using u32 = unsigned int;
typedef __attribute__((ext_vector_type(4))) float f32x4;
typedef __attribute__((ext_vector_type(8))) short short8;
typedef __attribute__((ext_vector_type(4))) u16 u16x4;
typedef __attribute__((ext_vector_type(8))) u16 u16x8;

// ---------- helpers ----------
__device__ __forceinline__ u16 f2bf(float f) {
  u32 u = __builtin_bit_cast(u32, f);
  u += 0x7FFFu + ((u >> 16) & 1u);
  return (u16)(u >> 16);
}
__device__ __forceinline__ float bf2f(u16 x) {
  return __builtin_bit_cast(float, (u32)x << 16);
}

__device__ __forceinline__ void gload16(const void* g, void* l) {
  __builtin_amdgcn_global_load_lds(
      (const __attribute__((address_space(1))) void*)g,
      (__attribute__((address_space(3))) void*)l, 16, 0, 0);
}

__device__ __forceinline__ float fast_tanh(float x) {
  float ax = fabsf(x);
  float e = __expf(-2.0f * ax);
  float r = (1.0f - e) / (1.0f + e);
  return x < 0.0f ? -r : r;
}

#define SBAR() do { asm volatile("" ::: "memory"); __builtin_amdgcn_s_barrier(); asm volatile("" ::: "memory"); } while (0)

// st_16x32 XOR swizzle on a byte offset (rows are 64 B; bit9 = row&8 -> bank spread)
__device__ __forceinline__ int swz(int L) { return L ^ (((L >> 9) & 1) << 5); }

// XCD-aware swizzle for 512 blocks (128 m-tiles x 4 n-tiles of 256)
__device__ __forceinline__ void swz_mn256(int bid, int& m0, int& n0) {
  int s = (bid & 7) * 64 + (bid >> 3);
  n0 = (s & 3) << 8;
  m0 = (s >> 2) << 8;
}

// ---------- fp32 -> bf16 convert ----------
__global__ void cvt_ker(const float4* __restrict__ src, u16x4* __restrict__ dst, int n4) {
  int i = blockIdx.x * 256 + threadIdx.x;
  if (i < n4) {
    float4 f = src[i];
    u16x4 o = { f2bf(f.x), f2bf(f.y), f2bf(f.z), f2bf(f.w) };
    dst[i] = o;
  }
}

// ---------- 256x256 GEMM mainloop, BK=32, 2 phases/tile, 2 blocks/CU ----------
// C[m][n] += sum_k A[m][k]*B[n][k], A/B bf16 row-major (BT form), K tiles of 32.
// 512 threads = 8 waves (2 wr x 4 wc); per-wave C 128x64 = acc[8][4] of 16x16.
// LDS 64 KiB: [buf:2][half:2][8192 elems]; half 0=B (256x32), 1=A (256x32).
// Unit stream S[j]: tile j>>1, half j&1. Phase (t,p) stages S[2t+p+3].
// vmcnt(2) per tile end (1 unit = 2 loads in flight); vmcnt(0) before last tile.
__device__ __forceinline__ void stage_half(
    const u16* __restrict__ A0, const u16* __restrict__ B0,
    const u16* __restrict__ A1, const u16* __restrict__ B1,
    int half_nt, u16* lds, int j, int m0, int n0, int w, int rc0, int rc1)
{
  int jt = j >> 1, isA = j & 1;
  const u16* src;
  int kt;
  if (jt < half_nt) { src = isA ? A0 : B0; kt = jt; }
  else              { src = isA ? A1 : B1; kt = jt - half_nt; }
  int base_row = isA ? m0 : n0;
  u16* dst = lds + ((jt & 1) * 2 + isA) * 8192 + w * 512;
  const u16* g0 = src + (size_t)base_row * 1024 + kt * 32;
  gload16(g0 + rc0, dst);
  gload16(g0 + rc1, dst + 4096);
}

__device__ __forceinline__ void gemm_loop(
    const u16* __restrict__ A0, const u16* __restrict__ B0,
    const u16* __restrict__ A1, const u16* __restrict__ B1,
    int half_nt, int NT, int m0, int n0, u16* lds, f32x4 acc[8][4])
{
  const int tid = threadIdx.x;
  const int w = tid >> 6, lane = tid & 63;
  const int wr = w >> 2, wc = w & 3;
  const int lr = lane & 15, g = lane >> 4;

  // per-thread inverse-swizzled global (row*1024+col) offsets for the 2 stage insts
  int rc0, rc1;
  {
    int seg0 = w * 64 + lane, seg1 = 512 + w * 64 + lane;
    int L0 = swz(seg0 * 16), L1 = swz(seg1 * 16);
    rc0 = (L0 >> 6) * 1024 + ((L0 & 63) >> 1);
    rc1 = (L1 >> 6) * 1024 + ((L1 & 63) >> 1);
  }
  // swizzled ds_read byte offsets within a half (rows 64 B)
  int aoff[8], boff[4];
  #pragma unroll
  for (int mi = 0; mi < 8; mi++)
    aoff[mi] = swz((wr * 128 + mi * 16 + lr) * 64 + g * 16);
  #pragma unroll
  for (int ni = 0; ni < 4; ni++)
    boff[ni] = swz((wc * 64 + ni * 16 + lr) * 64 + g * 16);

  // prologue: stage S[0..2] (tile0 B,A + tile1 B), wait tile0, barrier
  stage_half(A0, B0, A1, B1, half_nt, lds, 0, m0, n0, w, rc0, rc1);
  stage_half(A0, B0, A1, B1, half_nt, lds, 1, m0, n0, w, rc0, rc1);
  stage_half(A0, B0, A1, B1, half_nt, lds, 2, m0, n0, w, rc0, rc1);
  asm volatile("s_waitcnt vmcnt(2)" ::: "memory");
  SBAR();

  auto do_tile = [&](int t, int buf) {
    const char* halfB = (const char*)(lds + (buf * 2) * 8192);
    const char* halfA = (const char*)(lds + (buf * 2 + 1) * 8192);
    short8 bb0, bb1, bb2, bb3;
    #pragma unroll
    for (int p = 0; p < 2; ++p) {
      if (p == 0) {
        bb0 = *(const short8*)(halfB + boff[0]);
        bb1 = *(const short8*)(halfB + boff[1]);
        bb2 = *(const short8*)(halfB + boff[2]);
        bb3 = *(const short8*)(halfB + boff[3]);
      }
      short8 a0 = *(const short8*)(halfA + aoff[p * 4 + 0]);
      short8 a1 = *(const short8*)(halfA + aoff[p * 4 + 1]);
      short8 a2 = *(const short8*)(halfA + aoff[p * 4 + 2]);
      short8 a3 = *(const short8*)(halfA + aoff[p * 4 + 3]);

      int j = 2 * t + p + 3;
      if (j < 2 * NT)
        stage_half(A0, B0, A1, B1, half_nt, lds, j, m0, n0, w, rc0, rc1);

      SBAR();
      __builtin_amdgcn_s_setprio(1);
      #pragma unroll
      for (int ni = 0; ni < 4; ni++) {
        short8 b = ni == 0 ? bb0 : ni == 1 ? bb1 : ni == 2 ? bb2 : bb3;
        acc[p * 4 + 0][ni] = __builtin_amdgcn_mfma_f32_16x16x32_bf16(a0, b, acc[p * 4 + 0][ni], 0, 0, 0);
        acc[p * 4 + 1][ni] = __builtin_amdgcn_mfma_f32_16x16x32_bf16(a1, b, acc[p * 4 + 1][ni], 0, 0, 0);
        acc[p * 4 + 2][ni] = __builtin_amdgcn_mfma_f32_16x16x32_bf16(a2, b, acc[p * 4 + 2][ni], 0, 0, 0);
        acc[p * 4 + 3][ni] = __builtin_amdgcn_mfma_f32_16x16x32_bf16(a3, b, acc[p * 4 + 3][ni], 0, 0, 0);
      }
      __builtin_amdgcn_s_setprio(0);
      if (p == 1 && t < NT - 1) {
        if (t == NT - 2) asm volatile("s_waitcnt vmcnt(0)" ::: "memory");
        else             asm volatile("s_waitcnt vmcnt(2)" ::: "memory");
      }
      SBAR();
    }
  };
  for (int t = 0; t < NT; t += 2) { do_tile(t, 0); do_tile(t + 1, 1); }
}

// ---------- GEMM1: h = tanh(Q@W1^T + V@W2^T + b1 + b2), bf16 out ----------
__global__ void __launch_bounds__(512, 4)
gemm1_ker(const u16* __restrict__ q, const u16* __restrict__ v,
          const u16* __restrict__ w1, const u16* __restrict__ w2,
          const float* __restrict__ b1, const float* __restrict__ b2,
          u16* __restrict__ H)
{
  __shared__ u16 lds[32768];
  int m0, n0;
  swz_mn256(blockIdx.x, m0, n0);
  f32x4 acc[8][4];
  #pragma unroll
  for (int mi = 0; mi < 8; mi++)
    #pragma unroll
    for (int ni = 0; ni < 4; ni++) acc[mi][ni] = (f32x4){0.f, 0.f, 0.f, 0.f};

  gemm_loop(q, w1, v, w2, 32, 64, m0, n0, lds, acc);

  int tid = threadIdx.x, w = tid >> 6, lane = tid & 63;
  int wr = w >> 2, wc = w & 3, lr = lane & 15, g = lane >> 4;
  #pragma unroll
  for (int ni = 0; ni < 4; ni++) {
    int col = n0 + wc * 64 + ni * 16 + lr;
    float bias = b1[col] + b2[col];
    #pragma unroll
    for (int mi = 0; mi < 8; mi++)
      #pragma unroll
      for (int r = 0; r < 4; r++) {
        int row = m0 + wr * 128 + mi * 16 + g * 4 + r;
        H[(size_t)row * 1024 + col] = f2bf(fast_tanh(acc[mi][ni][r] + bias));
      }
  }
}

// ---------- escore: e = exp(h@Vw^T + vb) -> e_bf16 + per-(nblk,row) partial sums ----------
__global__ void __launch_bounds__(512, 4)
escore_ker(const u16* __restrict__ h, const u16* __restrict__ vw,
           const float* __restrict__ vb, u16* __restrict__ E,
           float* __restrict__ partial)
{
  __shared__ u16 lds[32768];
  int m0, n0;
  swz_mn256(blockIdx.x, m0, n0);
  f32x4 acc[8][4];
  #pragma unroll
  for (int mi = 0; mi < 8; mi++)
    #pragma unroll
    for (int ni = 0; ni < 4; ni++) acc[mi][ni] = (f32x4){0.f, 0.f, 0.f, 0.f};

  gemm_loop(h, vw, h, vw, 32, 32, m0, n0, lds, acc);

  int tid = threadIdx.x, w = tid >> 6, lane = tid & 63;
  int wr = w >> 2, wc = w & 3, lr = lane & 15, g = lane >> 4;

  // e = exp(score + vb); |score| bounded ~17 so no max-subtraction needed (fp32 safe)
  #pragma unroll
  for (int ni = 0; ni < 4; ni++) {
    float vbc = vb[n0 + wc * 64 + ni * 16 + lr];
    #pragma unroll
    for (int mi = 0; mi < 8; mi++)
      #pragma unroll
      for (int r = 0; r < 4; r++)
        acc[mi][ni][r] = __expf(acc[mi][ni][r] + vbc);
  }

  // per-(nblk,row) partial sums: reduce ni in-reg, lr via shfl, wc via LDS
  float* ps = (float*)lds;   // [wc:4][row:256], unique writer per slot
  #pragma unroll
  for (int mi = 0; mi < 8; mi++) {
    #pragma unroll
    for (int r = 0; r < 4; r++) {
      float t = acc[mi][0][r] + acc[mi][1][r] + acc[mi][2][r] + acc[mi][3][r];
      t += __shfl_xor(t, 1, 64);
      t += __shfl_xor(t, 2, 64);
      t += __shfl_xor(t, 4, 64);
      t += __shfl_xor(t, 8, 64);
      if (lr == 0) ps[wc * 256 + wr * 128 + mi * 16 + g * 4 + r] = t;
    }
  }
  __syncthreads();
  if (tid < 256) {
    float s = ps[tid] + ps[256 + tid] + ps[512 + tid] + ps[768 + tid];
    partial[(size_t)(n0 >> 8) * 32768 + m0 + tid] = s;
  }

  // e -> bf16 direct scatter stores
  #pragma unroll
  for (int ni = 0; ni < 4; ni++) {
    int col = n0 + wc * 64 + ni * 16 + lr;
    #pragma unroll
    for (int mi = 0; mi < 8; mi++)
      #pragma unroll
      for (int r = 0; r < 4; r++) {
        int row = m0 + wr * 128 + mi * 16 + g * 4 + r;
        E[(size_t)row * 1024 + col] = f2bf(acc[mi][ni][r]);
      }
  }
}

// ---------- rowsum: inv[row] = 1/sum of 4 n-block partials ----------
__global__ void rowsum_ker(const float* __restrict__ partial, float* __restrict__ inv) {
  int r = blockIdx.x * 256 + threadIdx.x;
  float s = partial[r] + partial[32768 + r] + partial[65536 + r] + partial[98304 + r];
  inv[r] = 1.0f / s;
}

// ---------- wout: out_w = bf16(e) * inv[row], fp32 ----------
__global__ void wout_ker(const u16* __restrict__ E, const float* __restrict__ inv,
                         float* __restrict__ out) {
  int t = blockIdx.x * 256 + threadIdx.x;   // u16x8 chunk index; 4194304 total
  size_t base = (size_t)t * 8;
  float sc = inv[t >> 7];                    // 128 chunks per 1024-row
  u16x8 v = *(const u16x8*)(E + base);
  float4 o0, o1;
  o0.x = bf2f(v[0]) * sc; o0.y = bf2f(v[1]) * sc; o0.z = bf2f(v[2]) * sc; o0.w = bf2f(v[3]) * sc;
  o1.x = bf2f(v[4]) * sc; o1.y = bf2f(v[5]) * sc; o1.z = bf2f(v[6]) * sc; o1.w = bf2f(v[7]) * sc;
  *(float4*)(out + base) = o0;
  *(float4*)(out + base + 4) = o1;
}

// ---------- transpose v_bf per batch: [b][l][h] -> [b][h][l] ----------
__global__ void transpose_ker(const u16* __restrict__ in, u16* __restrict__ out) {
  __shared__ u16 tile[64][68];
  int b = blockIdx.z;
  int h0 = blockIdx.x * 64, l0 = blockIdx.y * 64;
  const u16* src = in + (size_t)b * 1048576;
  u16* dst = out + (size_t)b * 1048576;
  int t = threadIdx.x;
  #pragma unroll
  for (int i = 0; i < 4; i++) {
    int idx = i * 1024 + t * 4;
    int r = idx >> 6, c = idx & 63;
    *(u16x4*)&tile[r][c] = *(const u16x4*)&src[(size_t)(l0 + r) * 1024 + h0 + c];
  }
  __syncthreads();
  #pragma unroll
  for (int i = 0; i < 4; i++) {
    int idx = i * 1024 + t * 4;
    int hr = idx >> 6, lc = idx & 63;
    u16x4 val = { tile[lc][hr], tile[lc + 1][hr], tile[lc + 2][hr], tile[lc + 3][hr] };
    *(u16x4*)&dst[(size_t)(h0 + hr) * 1024 + l0 + lc] = val;
  }
}

// ---------- GEMM3: context[b] = (e[b] @ value[b]) * inv[row] ----------
__global__ void __launch_bounds__(512, 4)
gemm3_ker(const u16* __restrict__ E, const u16* __restrict__ vT,
          const float* __restrict__ inv, float* __restrict__ ctx)
{
  __shared__ u16 lds[32768];
  int m0, n0;
  swz_mn256(blockIdx.x, m0, n0);
  const u16* Bb = vT + (size_t)(m0 >> 10) * 1048576;   // 256 | 1024: tile never straddles batches
  f32x4 acc[8][4];
  #pragma unroll
  for (int mi = 0; mi < 8; mi++)
    #pragma unroll
    for (int ni = 0; ni < 4; ni++) acc[mi][ni] = (f32x4){0.f, 0.f, 0.f, 0.f};

  gemm_loop(E, Bb, E, Bb, 32, 32, m0, n0, lds, acc);

  int tid = threadIdx.x, w = tid >> 6, lane = tid & 63;
  int wr = w >> 2, wc = w & 3, lr = lane & 15, g = lane >> 4;
  #pragma unroll
  for (int mi = 0; mi < 8; mi++) {
    #pragma unroll
    for (int r = 0; r < 4; r++) {
      int row = m0 + wr * 128 + mi * 16 + g * 4 + r;
      float sc = inv[row];
      #pragma unroll
      for (int ni = 0; ni < 4; ni++) {
        int col = n0 + wc * 64 + ni * 16 + lr;
        ctx[(size_t)row * 1024 + col] = acc[mi][ni][r] * sc;
      }
    }
  }
}

// ---------- launch ----------
extern "C" void kernel_launch(void* const* d_in, const int* in_sizes, int n_in,
                              void* d_out, int out_size, void* d_ws, size_t ws_size,
                              hipStream_t stream) {
  const float* q   = (const float*)d_in[0];
  // d_in[1] = key, unused by reference
  const float* v   = (const float*)d_in[2];
  const float* w1w = (const float*)d_in[3];
  const float* b1  = (const float*)d_in[4];
  const float* w2w = (const float*)d_in[5];
  const float* b2  = (const float*)d_in[6];
  const float* vww = (const float*)d_in[7];
  const float* vb  = (const float*)d_in[8];

  float* out_w = (float*)d_out;                 // attention_weights (32,1024,1024) fp32
  float* out_c = out_w + (size_t)33554432;      // context          (32,1024,1024) fp32

  u16* q_bf  = (u16*)d_ws;
  u16* v_bf  = q_bf + 33554432;
  u16* h_bf  = v_bf + 33554432;
  u16* w1_bf = h_bf + 33554432;
  u16* w2_bf = w1_bf + 1048576;
  u16* vw_bf = w2_bf + 1048576;
  u16* wsm_bf = q_bf;                   // e bf16: reuse q region (dead after gemm1)
  u16* vT_bf  = h_bf;                   // transposed V: reuse h region (dead after escore)
  float* partial = (float*)w1_bf;       // 512 KB (w1 dead after gemm1)
  float* invp    = (float*)w2_bf;       // 128 KB (w2 dead after gemm1)

  if (ws_size < (size_t)207618048) return;

  cvt_ker<<<32768, 256, 0, stream>>>((const float4*)q,   (u16x4*)q_bf,  8388608);
  cvt_ker<<<32768, 256, 0, stream>>>((const float4*)v,   (u16x4*)v_bf,  8388608);
  cvt_ker<<<1024,  256, 0, stream>>>((const float4*)w1w, (u16x4*)w1_bf, 262144);
  cvt_ker<<<1024,  256, 0, stream>>>((const float4*)w2w, (u16x4*)w2_bf, 262144);
  cvt_ker<<<1024,  256, 0, stream>>>((const float4*)vww, (u16x4*)vw_bf, 262144);

  gemm1_ker<<<512, 512, 0, stream>>>(q_bf, v_bf, w1_bf, w2_bf, b1, b2, h_bf);
  escore_ker<<<512, 512, 0, stream>>>(h_bf, vw_bf, vb, wsm_bf, partial);
  rowsum_ker<<<128, 256, 0, stream>>>(partial, invp);
  transpose_ker<<<dim3(16, 16, 32), 256, 0, stream>>>(v_bf, vT_bf);
  wout_ker<<<16384, 256, 0, stream>>>(wsm_bf, invp, out_w);
  gemm3_ker<<<512, 512, 0, stream>>>(wsm_bf, vT_bf, invp, out_c);
}

// Round 6
// 455.923 us; speedup vs baseline: 5.7158x; 5.7158x over previous
//
#include <hip/hip_runtime.h>
#include <cstdint>

using u16 = unsigned short;
using u32 = unsigned int;
typedef __attribute__((ext_vector_type(4))) float f32x4;
typedef __attribute__((ext_vector_type(8))) short short8;
typedef __attribute__((ext_vector_type(4))) u16 u16x4;
typedef __attribute__((ext_vector_type(8))) u16 u16x8;

// ---------- helpers ----------
__device__ __forceinline__ u16 f2bf(float f) {
  u32 u = __builtin_bit_cast(u32, f);
  u += 0x7FFFu + ((u >> 16) & 1u);
  return (u16)(u >> 16);
}
__device__ __forceinline__ float bf2f(u16 x) {
  return __builtin_bit_cast(float, (u32)x << 16);
}

__device__ __forceinline__ void gload16(const void* g, void* l) {
  __builtin_amdgcn_global_load_lds(
      (const __attribute__((address_space(1))) void*)g,
      (__attribute__((address_space(3))) void*)l, 16, 0, 0);
}

__device__ __forceinline__ float fast_tanh(float x) {
  float ax = fabsf(x);
  float e = __expf(-2.0f * ax);
  float r = (1.0f - e) / (1.0f + e);
  return x < 0.0f ? -r : r;
}

#define SBAR() do { asm volatile("" ::: "memory"); __builtin_amdgcn_s_barrier(); asm volatile("" ::: "memory"); } while (0)

template<int N> __device__ __forceinline__ void vmw() {
  if constexpr (N == 10) asm volatile("s_waitcnt vmcnt(10)" ::: "memory");
  else if constexpr (N == 8) asm volatile("s_waitcnt vmcnt(8)" ::: "memory");
  else if constexpr (N == 6) asm volatile("s_waitcnt vmcnt(6)" ::: "memory");
  else if constexpr (N == 4) asm volatile("s_waitcnt vmcnt(4)" ::: "memory");
  else if constexpr (N == 2) asm volatile("s_waitcnt vmcnt(2)" ::: "memory");
  else if constexpr (N == 0) asm volatile("s_waitcnt vmcnt(0)" ::: "memory");
  // N == -1: no wait
}

// st_16x32 XOR swizzle on a byte offset within a 16 KiB half-tile
__device__ __forceinline__ int swz(int L) { return L ^ (((L >> 9) & 1) << 5); }

// XCD-aware swizzle for 512 blocks (128 m-tiles x 4 n-tiles of 256)
__device__ __forceinline__ void swz_mn256(int bid, int& m0, int& n0) {
  int s = (bid & 7) * 64 + (bid >> 3);
  n0 = (s & 3) << 8;
  m0 = (s >> 2) << 8;
}

// ---------- fp32 -> bf16 convert ----------
__global__ void cvt_ker(const float4* __restrict__ src, u16x4* __restrict__ dst, int n4) {
  int i = blockIdx.x * 256 + threadIdx.x;
  if (i < n4) {
    float4 f = src[i];
    u16x4 o = { f2bf(f.x), f2bf(f.y), f2bf(f.z), f2bf(f.w) };
    dst[i] = o;
  }
}

// ---------- 256x256 GEMM mainloop, BK=64, SW-PIPELINED ds_reads (1 phase ahead) ----------
// C[m][n] += sum_k A[m][k]*B[n][k], A/B bf16 row-major (BT form), K tiles of 64.
// 512 threads = 8 waves (2 wr x 4 wc); per-wave C 128x64 = acc[8][4] of 16x16.
// LDS 128 KiB: [buf:2][half:4][8192 elems]; half 0=B.kk0 1=A.kk0 2=B.kk1 3=A.kk1.
// Stage stream S[j] (jt=j>>2, hh=j&3): prologue stages S[0..6]; phase G stages S[G+7].
// Reads pipelined: phase G issues ds_reads for phase G+1's MFMA; MFMA(G) consumes
// registers loaded at G-1 (compiler inserts counted lgkmcnt). ONE barrier per phase.
// Steady vmcnt(8) at phase end (4 staged halves in flight); exact tail peel.
__device__ __forceinline__ void stage_half(
    const u16* __restrict__ A0, const u16* __restrict__ B0,
    const u16* __restrict__ A1, const u16* __restrict__ B1,
    int half_nt, u16* lds, int j, int m0, int n0, int w, int rc0, int rc1)
{
  int jt = j >> 2, hh = j & 3;
  int kk = hh >> 1, isA = hh & 1;
  const u16* src;
  int kt;
  if (jt < half_nt) { src = isA ? A0 : B0; kt = jt; }
  else              { src = isA ? A1 : B1; kt = jt - half_nt; }
  int base_row = isA ? m0 : n0;
  int koff = kt * 64 + kk * 32;
  u16* dst = lds + ((jt & 1) * 4 + hh) * 8192 + w * 512;
  const u16* g0 = src + (size_t)base_row * 1024 + koff;
  gload16(g0 + rc0, dst);
  gload16(g0 + rc1, dst + 4096);
}

__device__ __forceinline__ void rdB4(short8* d, const u16* lds, int buf, int kk, const int* boff) {
  const char* h = (const char*)(lds + (buf * 4 + kk * 2) * 8192);
  d[0] = *(const short8*)(h + boff[0]);
  d[1] = *(const short8*)(h + boff[1]);
  d[2] = *(const short8*)(h + boff[2]);
  d[3] = *(const short8*)(h + boff[3]);
}
__device__ __forceinline__ void rdA4(short8* d, const u16* lds, int buf, int kk, int mh, const int* aoff) {
  const char* h = (const char*)(lds + (buf * 4 + 1 + kk * 2) * 8192);
  d[0] = *(const short8*)(h + aoff[mh * 4 + 0]);
  d[1] = *(const short8*)(h + aoff[mh * 4 + 1]);
  d[2] = *(const short8*)(h + aoff[mh * 4 + 2]);
  d[3] = *(const short8*)(h + aoff[mh * 4 + 3]);
}

#define MFMA16(AS, BS, BASE) do {                                                   \
  __builtin_amdgcn_s_setprio(1);                                                    \
  _Pragma("unroll")                                                                 \
  for (int ni_ = 0; ni_ < 4; ni_++) {                                               \
    acc[(BASE)+0][ni_] = __builtin_amdgcn_mfma_f32_16x16x32_bf16(AS[0], BS[ni_], acc[(BASE)+0][ni_], 0, 0, 0); \
    acc[(BASE)+1][ni_] = __builtin_amdgcn_mfma_f32_16x16x32_bf16(AS[1], BS[ni_], acc[(BASE)+1][ni_], 0, 0, 0); \
    acc[(BASE)+2][ni_] = __builtin_amdgcn_mfma_f32_16x16x32_bf16(AS[2], BS[ni_], acc[(BASE)+2][ni_], 0, 0, 0); \
    acc[(BASE)+3][ni_] = __builtin_amdgcn_mfma_f32_16x16x32_bf16(AS[3], BS[ni_], acc[(BASE)+3][ni_], 0, 0, 0); \
  }                                                                                 \
  __builtin_amdgcn_s_setprio(0);                                                    \
} while (0)

// One K-tile = 4 phases. Phase: [reads for next phase][stage][MFMA(cur)][vmcnt][bar]
#define TILE(T, V0, V1, V2, V3, S0_, S1_, S2_, S3_, NX) do {                        \
  const int buf_ = (T) & 1;                                                         \
  /* P0: mfma(kk0,mh0) on a0s,b0s; read a1s = A.mh1.kk0 */                          \
  rdA4(a1s, lds, buf_, 0, 1, aoff);                                                 \
  if (S0_) stage_half(A0, B0, A1, B1, half_nt, lds, 4 * (T) + 7, m0, n0, w, rc0, rc1); \
  MFMA16(a0s, b0s, 0);                                                              \
  vmw<V0>(); SBAR();                                                                \
  /* P1: mfma(kk0,mh1) on a1s,b0s; read b1s = B.kk1, a0s = A.mh0.kk1 */             \
  rdB4(b1s, lds, buf_, 1, boff);                                                    \
  rdA4(a0s, lds, buf_, 1, 0, aoff);                                                 \
  if (S1_) stage_half(A0, B0, A1, B1, half_nt, lds, 4 * (T) + 8, m0, n0, w, rc0, rc1); \
  MFMA16(a1s, b0s, 4);                                                              \
  vmw<V1>(); SBAR();                                                                \
  /* P2: mfma(kk1,mh0) on a0s,b1s; read a1s = A.mh1.kk1 */                          \
  rdA4(a1s, lds, buf_, 1, 1, aoff);                                                 \
  if (S2_) stage_half(A0, B0, A1, B1, half_nt, lds, 4 * (T) + 9, m0, n0, w, rc0, rc1); \
  MFMA16(a0s, b1s, 0);                                                              \
  vmw<V2>(); SBAR();                                                                \
  /* P3: mfma(kk1,mh1) on a1s,b1s; read next tile's b0s = B.kk0, a0s = A.mh0.kk0 */ \
  if (NX) { rdB4(b0s, lds, buf_ ^ 1, 0, boff); rdA4(a0s, lds, buf_ ^ 1, 0, 0, aoff); } \
  if (S3_) stage_half(A0, B0, A1, B1, half_nt, lds, 4 * (T) + 10, m0, n0, w, rc0, rc1); \
  MFMA16(a1s, b1s, 4);                                                              \
  vmw<V3>(); SBAR();                                                                \
} while (0)

__device__ __forceinline__ void gemm_loop(
    const u16* __restrict__ A0, const u16* __restrict__ B0,
    const u16* __restrict__ A1, const u16* __restrict__ B1,
    int half_nt, int NT, int m0, int n0, u16* lds, f32x4 acc[8][4])
{
  const int tid = threadIdx.x;
  const int w = tid >> 6, lane = tid & 63;
  const int wr = w >> 2, wc = w & 3;
  const int lr = lane & 15, g = lane >> 4;

  // per-thread inverse-swizzled global (row*1024+col) offsets for the 2 stage insts
  int rc0, rc1;
  {
    int seg0 = w * 64 + lane, seg1 = 512 + w * 64 + lane;
    int L0 = swz(seg0 * 16), L1 = swz(seg1 * 16);
    rc0 = (L0 >> 6) * 1024 + ((L0 & 63) >> 1);
    rc1 = (L1 >> 6) * 1024 + ((L1 & 63) >> 1);
  }
  // swizzled ds_read byte offsets within a half
  int aoff[8], boff[4];
  #pragma unroll
  for (int mi = 0; mi < 8; mi++)
    aoff[mi] = swz((wr * 128 + mi * 16 + lr) * 64 + g * 16);
  #pragma unroll
  for (int ni = 0; ni < 4; ni++)
    boff[ni] = swz((wc * 64 + ni * 16 + lr) * 64 + g * 16);

  short8 a0s[4], a1s[4], b0s[4], b1s[4];

  // prologue: stage S[0..6]; vmcnt(10) confirms S0,S1; barrier; pre-read tile0 p0 frags
  #pragma unroll
  for (int j = 0; j < 7; j++)
    stage_half(A0, B0, A1, B1, half_nt, lds, j, m0, n0, w, rc0, rc1);
  vmw<10>();
  SBAR();
  rdB4(b0s, lds, 0, 0, boff);
  rdA4(a0s, lds, 0, 0, 0, aoff);

  for (int t = 0; t < NT - 2; t += 2) {
    TILE(t,     8, 8, 8, 8, 1, 1, 1, 1, true);
    TILE(t + 1, 8, 8, 8, 8, 1, 1, 1, 1, true);
  }
  TILE(NT - 2, 8, 8, 4, 4, 1, 0, 0, 0, true);
  TILE(NT - 1, 0, 0, -1, -1, 0, 0, 0, 0, false);
}

// ---------- GEMM1: h = tanh(Q@W1^T + V@W2^T + b1 + b2), bf16 out ----------
__global__ void __launch_bounds__(512, 2)
gemm1_ker(const u16* __restrict__ q, const u16* __restrict__ v,
          const u16* __restrict__ w1, const u16* __restrict__ w2,
          const float* __restrict__ b1, const float* __restrict__ b2,
          u16* __restrict__ H)
{
  __shared__ u16 lds[65536];
  int m0, n0;
  swz_mn256(blockIdx.x, m0, n0);
  f32x4 acc[8][4];
  #pragma unroll
  for (int mi = 0; mi < 8; mi++)
    #pragma unroll
    for (int ni = 0; ni < 4; ni++) acc[mi][ni] = (f32x4){0.f, 0.f, 0.f, 0.f};

  gemm_loop(q, w1, v, w2, 16, 32, m0, n0, lds, acc);

  int tid = threadIdx.x, w = tid >> 6, lane = tid & 63;
  int wr = w >> 2, wc = w & 3, lr = lane & 15, g = lane >> 4;
  #pragma unroll
  for (int ni = 0; ni < 4; ni++) {
    int col = n0 + wc * 64 + ni * 16 + lr;
    float bias = b1[col] + b2[col];
    #pragma unroll
    for (int mi = 0; mi < 8; mi++)
      #pragma unroll
      for (int r = 0; r < 4; r++) {
        int row = m0 + wr * 128 + mi * 16 + g * 4 + r;
        H[(size_t)row * 1024 + col] = f2bf(fast_tanh(acc[mi][ni][r] + bias));
      }
  }
}

// ---------- escore: e = exp(h@Vw^T + vb) -> e_bf16 + per-(nblk,row) partial sums ----------
__global__ void __launch_bounds__(512, 2)
escore_ker(const u16* __restrict__ h, const u16* __restrict__ vw,
           const float* __restrict__ vb, u16* __restrict__ E,
           float* __restrict__ partial)
{
  __shared__ u16 lds[65536];
  int m0, n0;
  swz_mn256(blockIdx.x, m0, n0);
  f32x4 acc[8][4];
  #pragma unroll
  for (int mi = 0; mi < 8; mi++)
    #pragma unroll
    for (int ni = 0; ni < 4; ni++) acc[mi][ni] = (f32x4){0.f, 0.f, 0.f, 0.f};

  gemm_loop(h, vw, h, vw, 16, 16, m0, n0, lds, acc);

  int tid = threadIdx.x, w = tid >> 6, lane = tid & 63;
  int wr = w >> 2, wc = w & 3, lr = lane & 15, g = lane >> 4;

  // e = exp(score + vb); |score| bounded ~17 so no max-subtraction needed (fp32 safe)
  #pragma unroll
  for (int ni = 0; ni < 4; ni++) {
    float vbc = vb[n0 + wc * 64 + ni * 16 + lr];
    #pragma unroll
    for (int mi = 0; mi < 8; mi++)
      #pragma unroll
      for (int r = 0; r < 4; r++)
        acc[mi][ni][r] = __expf(acc[mi][ni][r] + vbc);
  }

  // per-(nblk,row) partial sums: reduce ni in-reg, lr via shfl, wc via LDS
  __syncthreads();            // all loop LDS traffic done before reuse as ps
  float* ps = (float*)lds;    // [wc:4][row:256], unique writer per slot
  #pragma unroll
  for (int mi = 0; mi < 8; mi++) {
    #pragma unroll
    for (int r = 0; r < 4; r++) {
      float t = acc[mi][0][r] + acc[mi][1][r] + acc[mi][2][r] + acc[mi][3][r];
      t += __shfl_xor(t, 1, 64);
      t += __shfl_xor(t, 2, 64);
      t += __shfl_xor(t, 4, 64);
      t += __shfl_xor(t, 8, 64);
      if (lr == 0) ps[wc * 256 + wr * 128 + mi * 16 + g * 4 + r] = t;
    }
  }
  __syncthreads();
  if (tid < 256) {
    float s = ps[tid] + ps[256 + tid] + ps[512 + tid] + ps[768 + tid];
    partial[(size_t)(n0 >> 8) * 32768 + m0 + tid] = s;
  }

  // e -> bf16 direct scatter stores
  #pragma unroll
  for (int ni = 0; ni < 4; ni++) {
    int col = n0 + wc * 64 + ni * 16 + lr;
    #pragma unroll
    for (int mi = 0; mi < 8; mi++)
      #pragma unroll
      for (int r = 0; r < 4; r++) {
        int row = m0 + wr * 128 + mi * 16 + g * 4 + r;
        E[(size_t)row * 1024 + col] = f2bf(acc[mi][ni][r]);
      }
  }
}

// ---------- rowsum: inv[row] = 1/sum of 4 n-block partials ----------
__global__ void rowsum_ker(const float* __restrict__ partial, float* __restrict__ inv) {
  int r = blockIdx.x * 256 + threadIdx.x;
  float s = partial[r] + partial[32768 + r] + partial[65536 + r] + partial[98304 + r];
  inv[r] = 1.0f / s;
}

// ---------- wout: out_w = bf16(e) * inv[row], fp32 ----------
__global__ void wout_ker(const u16* __restrict__ E, const float* __restrict__ inv,
                         float* __restrict__ out) {
  int t = blockIdx.x * 256 + threadIdx.x;   // u16x8 chunk index; 4194304 total
  size_t base = (size_t)t * 8;
  float sc = inv[t >> 7];                    // 128 chunks per 1024-row
  u16x8 v = *(const u16x8*)(E + base);
  float4 o0, o1;
  o0.x = bf2f(v[0]) * sc; o0.y = bf2f(v[1]) * sc; o0.z = bf2f(v[2]) * sc; o0.w = bf2f(v[3]) * sc;
  o1.x = bf2f(v[4]) * sc; o1.y = bf2f(v[5]) * sc; o1.z = bf2f(v[6]) * sc; o1.w = bf2f(v[7]) * sc;
  *(float4*)(out + base) = o0;
  *(float4*)(out + base + 4) = o1;
}

// ---------- transpose v_bf per batch: [b][l][h] -> [b][h][l] ----------
__global__ void transpose_ker(const u16* __restrict__ in, u16* __restrict__ out) {
  __shared__ u16 tile[64][68];
  int b = blockIdx.z;
  int h0 = blockIdx.x * 64, l0 = blockIdx.y * 64;
  const u16* src = in + (size_t)b * 1048576;
  u16* dst = out + (size_t)b * 1048576;
  int t = threadIdx.x;
  #pragma unroll
  for (int i = 0; i < 4; i++) {
    int idx = i * 1024 + t * 4;
    int r = idx >> 6, c = idx & 63;
    *(u16x4*)&tile[r][c] = *(const u16x4*)&src[(size_t)(l0 + r) * 1024 + h0 + c];
  }
  __syncthreads();
  #pragma unroll
  for (int i = 0; i < 4; i++) {
    int idx = i * 1024 + t * 4;
    int hr = idx >> 6, lc = idx & 63;
    u16x4 val = { tile[lc][hr], tile[lc + 1][hr], tile[lc + 2][hr], tile[lc + 3][hr] };
    *(u16x4*)&dst[(size_t)(h0 + hr) * 1024 + l0 + lc] = val;
  }
}

// ---------- GEMM3: context[b] = (e[b] @ value[b]) * inv[row] ----------
__global__ void __launch_bounds__(512, 2)
gemm3_ker(const u16* __restrict__ E, const u16* __restrict__ vT,
          const float* __restrict__ inv, float* __restrict__ ctx)
{
  __shared__ u16 lds[65536];
  int m0, n0;
  swz_mn256(blockIdx.x, m0, n0);
  const u16* Bb = vT + (size_t)(m0 >> 10) * 1048576;   // 256 | 1024: tile never straddles batches
  f32x4 acc[8][4];
  #pragma unroll
  for (int mi = 0; mi < 8; mi++)
    #pragma unroll
    for (int ni = 0; ni < 4; ni++) acc[mi][ni] = (f32x4){0.f, 0.f, 0.f, 0.f};

  gemm_loop(E, Bb, E, Bb, 16, 16, m0, n0, lds, acc);

  int tid = threadIdx.x, w = tid >> 6, lane = tid & 63;
  int wr = w >> 2, wc = w & 3, lr = lane & 15, g = lane >> 4;
  #pragma unroll
  for (int mi = 0; mi < 8; mi++) {
    #pragma unroll
    for (int r = 0; r < 4; r++) {
      int row = m0 + wr * 128 + mi * 16 + g * 4 + r;
      float sc = inv[row];
      #pragma unroll
      for (int ni = 0; ni < 4; ni++) {
        int col = n0 + wc * 64 + ni * 16 + lr;
        ctx[(size_t)row * 1024 + col] = acc[mi][ni][r] * sc;
      }
    }
  }
}

// ---------- launch ----------
extern "C" void kernel_launch(void* const* d_in, const int* in_sizes, int n_in,
                              void* d_out, int out_size, void* d_ws, size_t ws_size,
                              hipStream_t stream) {
  const float* q   = (const float*)d_in[0];
  // d_in[1] = key, unused by reference
  const float* v   = (const float*)d_in[2];
  const float* w1w = (const float*)d_in[3];
  const float* b1  = (const float*)d_in[4];
  const float* w2w = (const float*)d_in[5];
  const float* b2  = (const float*)d_in[6];
  const float* vww = (const float*)d_in[7];
  const float* vb  = (const float*)d_in[8];

  float* out_w = (float*)d_out;                 // attention_weights (32,1024,1024) fp32
  float* out_c = out_w + (size_t)33554432;      // context          (32,1024,1024) fp32

  u16* q_bf  = (u16*)d_ws;
  u16* v_bf  = q_bf + 33554432;
  u16* h_bf  = v_bf + 33554432;
  u16* w1_bf = h_bf + 33554432;
  u16* w2_bf = w1_bf + 1048576;
  u16* vw_bf = w2_bf + 1048576;
  u16* wsm_bf = q_bf;                   // e bf16: reuse q region (dead after gemm1)
  u16* vT_bf  = h_bf;                   // transposed V: reuse h region (dead after escore)
  float* partial = (float*)w1_bf;       // 512 KB (w1 dead after gemm1)
  float* invp    = (float*)w2_bf;       // 128 KB (w2 dead after gemm1)

  if (ws_size < (size_t)207618048) return;

  cvt_ker<<<32768, 256, 0, stream>>>((const float4*)q,   (u16x4*)q_bf,  8388608);
  cvt_ker<<<32768, 256, 0, stream>>>((const float4*)v,   (u16x4*)v_bf,  8388608);
  cvt_ker<<<1024,  256, 0, stream>>>((const float4*)w1w, (u16x4*)w1_bf, 262144);
  cvt_ker<<<1024,  256, 0, stream>>>((const float4*)w2w, (u16x4*)w2_bf, 262144);
  cvt_ker<<<1024,  256, 0, stream>>>((const float4*)vww, (u16x4*)vw_bf, 262144);

  gemm1_ker<<<512, 512, 0, stream>>>(q_bf, v_bf, w1_bf, w2_bf, b1, b2, h_bf);
  escore_ker<<<512, 512, 0, stream>>>(h_bf, vw_bf, vb, wsm_bf, partial);
  rowsum_ker<<<128, 256, 0, stream>>>(partial, invp);
  transpose_ker<<<dim3(16, 16, 32), 256, 0, stream>>>(v_bf, vT_bf);
  wout_ker<<<16384, 256, 0, stream>>>(wsm_bf, invp, out_w);
  gemm3_ker<<<512, 512, 0, stream>>>(wsm_bf, vT_bf, invp, out_c);
}